// Round 4
// baseline (452.822 us; speedup 1.0000x reference)
//
#include <hip/hip_runtime.h>
#include <hip/hip_bf16.h>
#include <stdint.h>

#define N 8192
#define D 128
#define NBLOCKS ((N / 64) * (N / 64))   // 16384 partial sums

typedef __bf16 bf16x8_t __attribute__((ext_vector_type(8)));
typedef __bf16 bf16x2_t __attribute__((ext_vector_type(2)));
typedef float  f32x4_t  __attribute__((ext_vector_type(4)));

// --- Kernel 1: row-normalize embeddings, cast to bf16 into workspace -------
__global__ __launch_bounds__(256) void normalize_k(const float* __restrict__ emb,
                                                   __bf16* __restrict__ xb) {
    const int row  = blockIdx.x * 4 + (threadIdx.x >> 6);
    const int lane = threadIdx.x & 63;
    const float2* src = reinterpret_cast<const float2*>(emb + (size_t)row * D);
    float2 v = src[lane];
    float ss = v.x * v.x + v.y * v.y;
#pragma unroll
    for (int off = 32; off; off >>= 1) ss += __shfl_xor(ss, off);
    const float inv = 1.0f / fmaxf(sqrtf(ss), 1e-8f);
    bf16x2_t o;
    o.x = (__bf16)(v.x * inv);
    o.y = (__bf16)(v.y * inv);
    *reinterpret_cast<bf16x2_t*>(xb + (size_t)row * D + lane * 2) = o;
}

// --- Kernel 2: fused X*X^T 64x64 tile + (pred - sim)^2 partial sum ---------
// DESIGN RULE (R3 post-mortem): every load's result must be LIVE in a
// register simultaneously -> no compiler-batched load/wait/consume chains
// exposing serial HBM latency. Per thread: 16 sim floats (16 regs, all in
// flight under one waitcnt staircase), a-frags 16 regs, b-frags 32 regs
// (double-buffered per K-step), acc 16. Peak ~100 regs -> 4 waves/SIMD.
// Wave w computes rows [w*16,w*16+16) x cols [0,64) of the block tile.
__global__ __launch_bounds__(256, 4) void gemm_loss_k(const __bf16* __restrict__ xb,
                                                      const float* __restrict__ sim,
                                                      float* __restrict__ partials) {
    const int lane = threadIdx.x & 63;
    const int wave = threadIdx.x >> 6;
    const int m = lane & 15;   // fragment row (A) / col (B); also C col
    const int q = lane >> 4;   // k-quad; also C row-quad
    const int i_base = blockIdx.y * 64 + wave * 16;
    const int j_base = blockIdx.x * 64;

    // ---- a-frags for all K (16 regs): row i_base+m, k-offset kk*32+q*8 ----
    bf16x8_t a[4];
#pragma unroll
    for (int kk = 0; kk < 4; ++kk)
        a[kk] = *reinterpret_cast<const bf16x8_t*>(
            xb + (size_t)(i_base + m) * D + kk * 32 + q * 8);

    // ---- b-frags: double-buffered across K-steps (32 regs live) ----
    bf16x8_t b0[4], b1[4];
#pragma unroll
    for (int s = 0; s < 4; ++s)
        b0[s] = *reinterpret_cast<const bf16x8_t*>(
            xb + (size_t)(j_base + s * 16 + m) * D + q * 8);

    const f32x4_t zero = {0.0f, 0.0f, 0.0f, 0.0f};
    f32x4_t acc[4];
#pragma unroll
    for (int s = 0; s < 4; ++s) acc[s] = zero;

#pragma unroll
    for (int kk = 0; kk < 4; ++kk) {
        bf16x8_t* bc = (kk & 1) ? b1 : b0;
        bf16x8_t* bn = (kk & 1) ? b0 : b1;
        if (kk < 3) {
            const int kofs = (kk + 1) * 32 + q * 8;
#pragma unroll
            for (int s = 0; s < 4; ++s)
                bn[s] = *reinterpret_cast<const bf16x8_t*>(
                    xb + (size_t)(j_base + s * 16 + m) * D + kofs);
        }
#pragma unroll
        for (int s = 0; s < 4; ++s)
            acc[s] = __builtin_amdgcn_mfma_f32_16x16x32_bf16(a[kk], bc[s], acc[s], 0, 0, 0);
    }

    // ---- sim loads: 16 per thread, ALL live (16 regs), one wait ----
    // C/D layout: col = j_base + s*16 + m, row = i_base + q*4 + r.
    float sv[4][4];
#pragma unroll
    for (int s = 0; s < 4; ++s)
#pragma unroll
        for (int r = 0; r < 4; ++r)
            sv[s][r] = sim[(size_t)(i_base + q * 4 + r) * N + (j_base + s * 16 + m)];

    float local = 0.0f;
#pragma unroll
    for (int s = 0; s < 4; ++s)
#pragma unroll
        for (int r = 0; r < 4; ++r) {
            const float d = acc[s][r] - sv[s][r];
            local = fmaf(d, d, local);
        }
#pragma unroll
    for (int off = 32; off; off >>= 1) local += __shfl_xor(local, off);
    __shared__ float wsum[4];
    if (lane == 0) wsum[wave] = local;
    __syncthreads();
    if (threadIdx.x == 0) {
        const int bid = blockIdx.y * gridDim.x + blockIdx.x;
        partials[bid] = wsum[0] + wsum[1] + wsum[2] + wsum[3];
    }
}

// --- Kernel 3: reduce 16384 partials, finalize ------------------------------
__global__ __launch_bounds__(256) void finalize_k(const float* __restrict__ partials,
                                                  float* __restrict__ out) {
    float s = 0.0f;
#pragma unroll
    for (int i = 0; i < NBLOCKS / 256; ++i)
        s += partials[i * 256 + threadIdx.x];
#pragma unroll
    for (int off = 32; off; off >>= 1) s += __shfl_xor(s, off);
    __shared__ float wsum[4];
    if ((threadIdx.x & 63) == 0) wsum[threadIdx.x >> 6] = s;
    __syncthreads();
    if (threadIdx.x == 0)
        out[0] = (wsum[0] + wsum[1] + wsum[2] + wsum[3])
                 * (1.0f / ((float)N * (float)N));
}

extern "C" void kernel_launch(void* const* d_in, const int* in_sizes, int n_in,
                              void* d_out, int out_size, void* d_ws, size_t ws_size,
                              hipStream_t stream) {
    const float* emb = (const float*)d_in[0];
    const float* sim = (const float*)d_in[1];
    __bf16* xb = (__bf16*)d_ws;                                   // 2 MB bf16 x
    float* partials = (float*)((char*)d_ws + (size_t)N * D * sizeof(__bf16));

    normalize_k<<<N / 4, 256, 0, stream>>>(emb, xb);
    gemm_loss_k<<<dim3(N / 64, N / 64), 256, 0, stream>>>(xb, sim, partials);
    finalize_k<<<1, 256, 0, stream>>>(partials, (float*)d_out);
}

// Round 5
// 411.072 us; speedup vs baseline: 1.1016x; 1.1016x over previous
//
#include <hip/hip_runtime.h>
#include <hip/hip_bf16.h>
#include <stdint.h>

#define N 8192
#define D 128
#define JSEG 512                   // sim columns per block
#define JT   16                    // cols per j-iteration
#define ITERS (JSEG / JT)          // 32
#define GRID_X (N / JSEG)          // 16
#define GRID_Y (N / 64)            // 128 (64 rows per block)
#define NBLOCKS (GRID_X * GRID_Y)  // 2048 partials

typedef __bf16 bf16x8_t __attribute__((ext_vector_type(8)));
typedef __bf16 bf16x2_t __attribute__((ext_vector_type(2)));
typedef float  f32x4_t  __attribute__((ext_vector_type(4)));

// --- Kernel 1: row-normalize embeddings, cast to bf16 into workspace -------
__global__ __launch_bounds__(256) void normalize_k(const float* __restrict__ emb,
                                                   __bf16* __restrict__ xb) {
    const int row  = blockIdx.x * 4 + (threadIdx.x >> 6);
    const int lane = threadIdx.x & 63;
    const float2* src = reinterpret_cast<const float2*>(emb + (size_t)row * D);
    float2 v = src[lane];
    float ss = v.x * v.x + v.y * v.y;
#pragma unroll
    for (int off = 32; off; off >>= 1) ss += __shfl_xor(ss, off);
    const float inv = 1.0f / fmaxf(sqrtf(ss), 1e-8f);
    bf16x2_t o;
    o.x = (__bf16)(v.x * inv);
    o.y = (__bf16)(v.y * inv);
    *reinterpret_cast<bf16x2_t*>(xb + (size_t)row * D + lane * 2) = o;
}

// --- Kernel 2: persistent band-streaming fused GEMM + MSE partial ----------
// R4 post-mortem: one-shot blocks can't sustain HBM BW (one load burst then
// drain/retire). Here each wave owns a 16-row strip and STREAMS 32 j-tiles
// (16 cols each) in a software-pipelined loop: prefetch(jt+1) issues before
// the MFMAs of jt, so the in-order vmcnt wait for b[cur] (older loads) keeps
// the 8 prefetch loads of jt+1 in flight. Per-wave live set ~85 VGPR;
// 8 blocks/CU resident -> ~24 KB sim continuously in flight per CU.
__global__ __launch_bounds__(256, 4) void gemm_loss_k(const __bf16* __restrict__ xb,
                                                      const float* __restrict__ sim,
                                                      float* __restrict__ partials) {
    const int lane = threadIdx.x & 63;
    const int wave = threadIdx.x >> 6;
    const int m = lane & 15;   // A row / B col; C col
    const int q = lane >> 4;   // k-quad; C row-quad
    const int i0 = blockIdx.y * 64 + wave * 16;
    const int j0 = blockIdx.x * JSEG;

    // a-frags: fixed all kernel (16 regs). A[m][k], k = kk*32 + q*8 + 0..7
    bf16x8_t a[4];
#pragma unroll
    for (int kk = 0; kk < 4; ++kk)
        a[kk] = *reinterpret_cast<const bf16x8_t*>(
            xb + (size_t)(i0 + m) * D + kk * 32 + q * 8);

    bf16x8_t b[2][4];   // ping-pong b-frags  (32 regs)
    float    sv[2][4];  // ping-pong sim vals (8 regs)

    // ---- prefetch iteration 0 ----
#pragma unroll
    for (int kk = 0; kk < 4; ++kk)
        b[0][kk] = *reinterpret_cast<const bf16x8_t*>(
            xb + (size_t)(j0 + m) * D + kk * 32 + q * 8);
#pragma unroll
    for (int r = 0; r < 4; ++r)
        sv[0][r] = sim[(size_t)(i0 + q * 4 + r) * N + j0 + m];

    const f32x4_t zero = {0.0f, 0.0f, 0.0f, 0.0f};
    float local = 0.0f;

#pragma unroll 2
    for (int jt = 0; jt < ITERS; ++jt) {
        const int cur = jt & 1, nxt = cur ^ 1;
        // ---- prefetch jt+1 FIRST (stays in flight under the MFMAs) ----
        if (jt + 1 < ITERS) {
            const int j = j0 + (jt + 1) * JT;
#pragma unroll
            for (int kk = 0; kk < 4; ++kk)
                b[nxt][kk] = *reinterpret_cast<const bf16x8_t*>(
                    xb + (size_t)(j + m) * D + kk * 32 + q * 8);
#pragma unroll
            for (int r = 0; r < 4; ++r)
                sv[nxt][r] = sim[(size_t)(i0 + q * 4 + r) * N + j + m];
        }
        // ---- compute 16x16 pred tile for jt ----
        f32x4_t acc = zero;
#pragma unroll
        for (int kk = 0; kk < 4; ++kk)
            acc = __builtin_amdgcn_mfma_f32_16x16x32_bf16(a[kk], b[cur][kk], acc, 0, 0, 0);
        // ---- fused (pred - sim)^2 ----
#pragma unroll
        for (int r = 0; r < 4; ++r) {
            const float d = acc[r] - sv[cur][r];
            local = fmaf(d, d, local);
        }
    }

#pragma unroll
    for (int off = 32; off; off >>= 1) local += __shfl_xor(local, off);
    __shared__ float wsum[4];
    if (lane == 0) wsum[wave] = local;
    __syncthreads();
    if (threadIdx.x == 0) {
        const int bid = blockIdx.y * gridDim.x + blockIdx.x;
        partials[bid] = wsum[0] + wsum[1] + wsum[2] + wsum[3];
    }
}

// --- Kernel 3: reduce 2048 partials, finalize ------------------------------
__global__ __launch_bounds__(256) void finalize_k(const float* __restrict__ partials,
                                                  float* __restrict__ out) {
    float s = 0.0f;
#pragma unroll
    for (int i = 0; i < NBLOCKS / 256; ++i)
        s += partials[i * 256 + threadIdx.x];
#pragma unroll
    for (int off = 32; off; off >>= 1) s += __shfl_xor(s, off);
    __shared__ float wsum[4];
    if ((threadIdx.x & 63) == 0) wsum[threadIdx.x >> 6] = s;
    __syncthreads();
    if (threadIdx.x == 0)
        out[0] = (wsum[0] + wsum[1] + wsum[2] + wsum[3])
                 * (1.0f / ((float)N * (float)N));
}

extern "C" void kernel_launch(void* const* d_in, const int* in_sizes, int n_in,
                              void* d_out, int out_size, void* d_ws, size_t ws_size,
                              hipStream_t stream) {
    const float* emb = (const float*)d_in[0];
    const float* sim = (const float*)d_in[1];
    __bf16* xb = (__bf16*)d_ws;                                   // 2 MB bf16 x
    float* partials = (float*)((char*)d_ws + (size_t)N * D * sizeof(__bf16));

    normalize_k<<<N / 4, 256, 0, stream>>>(emb, xb);
    gemm_loss_k<<<dim3(GRID_X, GRID_Y), 256, 0, stream>>>(xb, sim, partials);
    finalize_k<<<1, 256, 0, stream>>>(partials, (float*)d_out);
}